// Round 13
// baseline (331.493 us; speedup 1.0000x reference)
//
#include <hip/hip_runtime.h>
#include <hip/hip_cooperative_groups.h>

namespace cg = cooperative_groups;

typedef __attribute__((ext_vector_type(8))) __bf16 bf16x8;
typedef __attribute__((ext_vector_type(4))) float f32x4;
typedef _Float16 f16x4 __attribute__((ext_vector_type(4)));
typedef unsigned int uint32;

#define HW   4096
#define CCH  64
#define DQ   32
#define OC   32
#define LOG2E 1.4426950408889634f

// Workspace layout (float offsets). Total ~32.5 MB.
#define WSV_OFF  0u
#define QB_OFF   2048u                    // bf16 [b][n][32] (pre-scaled log2e)
#define KB_OFF   (QB_OFF + 524288u)       // bf16 [b][m][32]
#define XS_OFF   (KB_OFF + 524288u)       // f32  [b][o][n]
#define V2_OFF   (XS_OFF + 1048576u)      // f32  [b][o][m]
#define ZP_OFF   (V2_OFF + 1048576u)      // f32  [8][b][m] partial Z
#define VZC_OFF  (ZP_OFF + 262144u)       // f16  [b][Mb][o][lq][ph][j] shuffled
#define OUTP_OFF (VZC_OFF + 524288u)      // bf16 [8][b][o][n] partial out

__device__ __forceinline__ uint32 f2bf(float x) {   // RNE
    uint32 u = __builtin_bit_cast(uint32, x);
    return (u + 0x7fffu + ((u >> 16) & 1u)) >> 16;
}
__device__ __forceinline__ uint32 packbf(float a, float b) {
    return f2bf(a) | (f2bf(b) << 16);
}
__device__ __forceinline__ bf16x8 ldfrag(const unsigned short* p) {
    union { uint4 u; bf16x8 f; } t;
    t.u = *(const uint4*)p;
    return t.f;
}
__device__ __forceinline__ bf16x8 asbf(uint4 u) {
    union { uint4 u; bf16x8 f; } t;
    t.u = u;
    return t.f;
}
__device__ __forceinline__ f16x4 u2h4(uint32 a, uint32 b) {
    union { uint2 u; f16x4 f; } t;
    t.u.x = a; t.u.y = b;
    return t.f;
}
__device__ __forceinline__ f16x4 pk4(float a, float b, float c, float d) {
    union { uint2 u; f16x4 f; } t;
    t.u.x = __builtin_bit_cast(uint32, __builtin_amdgcn_cvt_pkrtz(a, b));
    t.u.y = __builtin_bit_cast(uint32, __builtin_amdgcn_cvt_pkrtz(c, d));
    return t.f;
}
__device__ __forceinline__ float fexp2(float x) {
#if __has_builtin(__builtin_amdgcn_exp2f)
    return __builtin_amdgcn_exp2f(x);
#else
    return __expf(x * 0.6931471805599453f);
#endif
}

// ---------------------------------------------------------------------------
// shared phase bodies (used by both the fused kernel and the fallback)
__device__ __forceinline__ void proj_body(
    int p, int g,
    const float* __restrict__ x1, const float* __restrict__ x2,
    const float* __restrict__ Wq, const float* __restrict__ bq,
    const float* __restrict__ Wk, const float* __restrict__ bk,
    const float* __restrict__ Wsv, const float* __restrict__ Wsc,
    unsigned short* __restrict__ qb, unsigned short* __restrict__ kb,
    float* __restrict__ v2, float* __restrict__ xs) {
    int b = p >> 12, n = p & 4095;
    const float* x1b = x1 + (size_t)b * 32 * HW + n;
    const float* x2b = x2 + (size_t)b * 32 * HW + n;
    float x[CCH];
    #pragma unroll
    for (int c = 0; c < 32; ++c) x[c] = x1b[(size_t)c * HW];
    #pragma unroll
    for (int c = 0; c < 32; ++c) x[32 + c] = x2b[(size_t)c * HW];

    if (g < 2) {
        const float* W    = g ? Wk : Wq;
        const float* bias = g ? bk : bq;
        float scale = g ? 1.0f : LOG2E;
        unsigned short* dst = g ? kb : qb;
        size_t row = ((size_t)b * HW + n) * DQ;
        for (int d0 = 0; d0 < DQ; d0 += 8) {
            float r[8];
            #pragma unroll
            for (int i = 0; i < 8; ++i) {
                const float* wr = W + (d0 + i) * CCH;
                float a = bias[d0 + i];
                #pragma unroll
                for (int c = 0; c < CCH; ++c) a += wr[c] * x[c];
                r[i] = a * scale;
            }
            uint4 u;
            u.x = packbf(r[0], r[1]); u.y = packbf(r[2], r[3]);
            u.z = packbf(r[4], r[5]); u.w = packbf(r[6], r[7]);
            *(uint4*)(dst + row + d0) = u;
        }
    } else {
        const float* W = (g == 2) ? Wsv : Wsc;
        float* dst     = (g == 2) ? v2  : xs;
        for (int o = 0; o < OC; ++o) {
            const float* wr = W + o * CCH;
            float a = 0.f;
            #pragma unroll
            for (int c = 0; c < CCH; ++c) a += wr[c] * x[c];
            dst[((size_t)b * OC + o) * HW + n] = a;
        }
    }
}

__device__ __forceinline__ void stats_body(
    int unit, int w, int lr, int lq,
    const unsigned short* __restrict__ kb, const unsigned short* __restrict__ qb,
    float* __restrict__ zp) {
    int b = unit & 7, nc = (unit >> 3) & 7, mg = unit >> 6;   // mg 0..7
    int m0 = mg * 512 + w * 128;

    const unsigned short* kbb = kb + (size_t)b * HW * DQ;
    bf16x8 af[8];
    #pragma unroll
    for (int f = 0; f < 8; ++f)
        af[f] = ldfrag(kbb + (size_t)(m0 + f * 16 + lr) * DQ + lq * 8);

    const unsigned short* qp = qb + ((size_t)b * HW + nc * 512 + lr) * DQ + lq * 8;

    f32x4 acc[8];
    #pragma unroll
    for (int f = 0; f < 8; ++f) acc[f] = (f32x4){0.f, 0.f, 0.f, 0.f};
    f32x4 zz = {0.f, 0.f, 0.f, 0.f};

    uint4 q0 = *(const uint4*)qp;
    uint4 q1 = *(const uint4*)(qp + 16 * DQ);
    for (int i = 0; i < 32; ++i) {
        bf16x8 qf = asbf(q0);
        q0 = q1;
        if (i + 2 < 32) q1 = *(const uint4*)(qp + (size_t)(i + 2) * 16 * DQ);
        #pragma unroll
        for (int f = 0; f < 8; ++f) {
            f32x4 s = __builtin_amdgcn_mfma_f32_16x16x32_bf16(af[f], qf, zz, 0, 0, 0);
            acc[f].x += fexp2(s.x); acc[f].y += fexp2(s.y);
            acc[f].z += fexp2(s.z); acc[f].w += fexp2(s.w);
        }
    }
    #pragma unroll
    for (int f = 0; f < 8; ++f) {
        #pragma unroll
        for (int off = 1; off < 16; off <<= 1) {
            acc[f].x += __shfl_xor(acc[f].x, off);
            acc[f].y += __shfl_xor(acc[f].y, off);
            acc[f].z += __shfl_xor(acc[f].z, off);
            acc[f].w += __shfl_xor(acc[f].w, off);
        }
    }
    if (lr == 0) {
        size_t base = (size_t)nc * 32768 + (size_t)b * HW;
        #pragma unroll
        for (int f = 0; f < 8; ++f) {
            size_t p0 = base + m0 + f * 16 + lq * 4;
            zp[p0 + 0] = acc[f].x;
            zp[p0 + 1] = acc[f].y;
            zp[p0 + 2] = acc[f].z;
            zp[p0 + 3] = acc[f].w;
        }
    }
}

__device__ __forceinline__ void zvz_body(
    int idx, const float* __restrict__ zp, const float* __restrict__ v2,
    const float* __restrict__ gamma, unsigned short* __restrict__ vzc) {
    int i = idx >> 1, half = idx & 1;
    float s = 0.f;
    #pragma unroll
    for (int nc = 0; nc < 8; ++nc) s += zp[nc * 32768 + i];
    float zs = gamma[0] / s;
    int b = i >> 12, m = i & 4095;
    int Mb = m >> 5, mloc = m & 31;
    int ph = mloc >> 4, lqm = (mloc >> 2) & 3, j = mloc & 3;
    int o0 = half * 16;
    const float* vsrc = v2 + ((size_t)b * OC + o0) * HW + m;
    unsigned short* dst = vzc + (size_t)b * OC * HW + (size_t)Mb * 1024
                        + o0 * 32 + lqm * 8 + ph * 4 + j;
    #pragma unroll 8
    for (int o = 0; o < 16; ++o) {
        _Float16 h = (_Float16)(vsrc[(size_t)o * HW] * zs);
        dst[o * 32] = __builtin_bit_cast(unsigned short, h);
    }
}

__device__ __forceinline__ void attn_step(
    uint4 ck0, uint4 ck1, uint4 cv0, uint4 cv1,
    const bf16x8* qf, f32x4* acc0, f32x4* acc1, f32x4 zz) {
    #pragma unroll
    for (int ph = 0; ph < 2; ++ph) {
        bf16x8 a  = asbf(ph ? ck1 : ck0);
        f16x4 va0 = ph ? u2h4(cv0.z, cv0.w) : u2h4(cv0.x, cv0.y);
        f16x4 va1 = ph ? u2h4(cv1.z, cv1.w) : u2h4(cv1.x, cv1.y);
        #pragma unroll
        for (int tt = 0; tt < 8; ++tt) {
            f32x4 s = __builtin_amdgcn_mfma_f32_16x16x32_bf16(a, qf[tt], zz, 0, 0, 0);
            f16x4 p = pk4(fexp2(s.x), fexp2(s.y), fexp2(s.z), fexp2(s.w));
            acc0[tt] = __builtin_amdgcn_mfma_f32_16x16x16f16(va0, p, acc0[tt], 0, 0, 0);
            acc1[tt] = __builtin_amdgcn_mfma_f32_16x16x16f16(va1, p, acc1[tt], 0, 0, 0);
        }
    }
}

__device__ __forceinline__ void attn_body(
    int unit, int w, int lr, int lq,
    const unsigned short* __restrict__ qb, const unsigned short* __restrict__ kb,
    const unsigned short* __restrict__ vzc, unsigned short* __restrict__ outp) {
    int b = unit & 7, mc = (unit >> 3) & 7, ng = unit >> 6;   // ng 0..7
    int n0 = ng * 512 + w * 128;

    bf16x8 qf[8];
    #pragma unroll
    for (int tt = 0; tt < 8; ++tt)
        qf[tt] = ldfrag(qb + ((size_t)b * HW + n0 + tt * 16 + lr) * DQ + lq * 8);

    const unsigned short* kp = kb + ((size_t)b * HW + lr) * DQ + lq * 8;
    const unsigned short* vp = vzc + (size_t)b * OC * HW + lr * 32 + lq * 8;

    f32x4 acc0[8], acc1[8];
    #pragma unroll
    for (int tt = 0; tt < 8; ++tt) {
        acc0[tt] = (f32x4){0.f, 0.f, 0.f, 0.f};
        acc1[tt] = (f32x4){0.f, 0.f, 0.f, 0.f};
    }
    f32x4 zz = {0.f, 0.f, 0.f, 0.f};

    int mbeg = mc * 512;
    uint4 kA0 = *(const uint4*)(kp + (size_t)mbeg * DQ);
    uint4 kA1 = *(const uint4*)(kp + (size_t)(mbeg + 16) * DQ);
    uint4 vA0 = *(const uint4*)(vp + (size_t)(mbeg >> 5) * 1024);
    uint4 vA1 = *(const uint4*)(vp + (size_t)(mbeg >> 5) * 1024 + 512);
    uint4 kB0 = *(const uint4*)(kp + (size_t)(mbeg + 32) * DQ);
    uint4 kB1 = *(const uint4*)(kp + (size_t)(mbeg + 48) * DQ);
    uint4 vB0 = *(const uint4*)(vp + (size_t)((mbeg + 32) >> 5) * 1024);
    uint4 vB1 = *(const uint4*)(vp + (size_t)((mbeg + 32) >> 5) * 1024 + 512);

    for (int m0 = mbeg; m0 < mbeg + 512; m0 += 64) {
        uint4 ck0 = kA0, ck1 = kA1, cv0 = vA0, cv1 = vA1;
        if (m0 + 64 < mbeg + 512) {
            kA0 = *(const uint4*)(kp + (size_t)(m0 + 64) * DQ);
            kA1 = *(const uint4*)(kp + (size_t)(m0 + 80) * DQ);
            vA0 = *(const uint4*)(vp + (size_t)((m0 + 64) >> 5) * 1024);
            vA1 = *(const uint4*)(vp + (size_t)((m0 + 64) >> 5) * 1024 + 512);
        }
        attn_step(ck0, ck1, cv0, cv1, qf, acc0, acc1, zz);
        ck0 = kB0; ck1 = kB1; cv0 = vB0; cv1 = vB1;
        if (m0 + 96 < mbeg + 512) {
            kB0 = *(const uint4*)(kp + (size_t)(m0 + 96) * DQ);
            kB1 = *(const uint4*)(kp + (size_t)(m0 + 112) * DQ);
            vB0 = *(const uint4*)(vp + (size_t)((m0 + 96) >> 5) * 1024);
            vB1 = *(const uint4*)(vp + (size_t)((m0 + 96) >> 5) * 1024 + 512);
        }
        attn_step(ck0, ck1, cv0, cv1, qf, acc0, acc1, zz);
    }

    unsigned short* ob = outp + (size_t)(mc * 8 + b) * OC * HW;
    #pragma unroll
    for (int tt = 0; tt < 8; ++tt) {
        int n_t = n0 + tt * 16 + lr;
        #pragma unroll
        for (int r = 0; r < 4; ++r) {
            int o0 = lq * 4 + r;
            ob[(size_t)o0 * HW + n_t]        = (unsigned short)f2bf(acc0[tt][r]);
            ob[(size_t)(o0 + 16) * HW + n_t] = (unsigned short)f2bf(acc1[tt][r]);
        }
    }
}

__device__ __forceinline__ void red_body(
    int idx, const unsigned short* __restrict__ outp,
    const float* __restrict__ xs, float* __restrict__ out) {
    int i = idx * 4;
    float4 r = *(const float4*)(xs + i);
    const unsigned short* op = outp + i;
    #pragma unroll
    for (int mc = 0; mc < 8; ++mc) {
        uint2 p = *(const uint2*)(op + (size_t)mc * 1048576);
        r.x += __builtin_bit_cast(float, p.x << 16);
        r.y += __builtin_bit_cast(float, p.x & 0xffff0000u);
        r.z += __builtin_bit_cast(float, p.y << 16);
        r.w += __builtin_bit_cast(float, p.y & 0xffff0000u);
    }
    *(float4*)(out + i) = r;
}

// ===========================================================================
// Fused cooperative kernel: 256 blocks x 256 threads — 1 block/CU, co-resident
// at ANY register count, so the coop launch cannot fail on occupancy.
__global__ __launch_bounds__(256) void k_all(
    const float* __restrict__ x1, const float* __restrict__ x2,
    const float* __restrict__ Wq, const float* __restrict__ bq,
    const float* __restrict__ Wk, const float* __restrict__ bk,
    const float* __restrict__ Wv, const float* __restrict__ Wsc,
    const float* __restrict__ gamma, float* __restrict__ out,
    float* __restrict__ ws) {
    cg::grid_group grid = cg::this_grid();
    int bid = blockIdx.x;
    int t = threadIdx.x;
    int w = t >> 6, l = t & 63;
    int lr = l & 15, lq = l >> 4;

    float*          wsv  = ws + WSV_OFF;
    unsigned short* qb   = (unsigned short*)(ws + QB_OFF);
    unsigned short* kb   = (unsigned short*)(ws + KB_OFF);
    float*          xs   = ws + XS_OFF;
    float*          v2   = ws + V2_OFF;
    float*          zp   = ws + ZP_OFF;
    unsigned short* vzc  = (unsigned short*)(ws + VZC_OFF);
    unsigned short* outp = (unsigned short*)(ws + OUTP_OFF);

    // phase 0: Wsv = Wsc @ Wv (blocks 0..7)
    if (bid < 8) {
        int e = bid * 256 + t;
        int o = e >> 6, ci = e & 63;
        float s = 0.f;
        #pragma unroll
        for (int c = 0; c < CCH; ++c) s += Wsc[o * CCH + c] * Wv[c * CCH + ci];
        wsv[e] = s;
    }
    grid.sync();

    // phase 1: projections (2 sub-tiles per block)
    {
        int g = __builtin_amdgcn_readfirstlane(w);
        for (int rep = 0; rep < 2; ++rep)
            proj_body((bid * 2 + rep) * 64 + l, g, x1, x2, Wq, bq, Wk, bk,
                      wsv, Wsc, qb, kb, v2, xs);
    }
    grid.sync();

    // phase 2: partial Zp (2 units per block)
    for (int rep = 0; rep < 2; ++rep)
        stats_body(bid * 2 + rep, w, lr, lq, kb, qb, zp);
    grid.sync();

    // phase 3: zs + vzc (65536 threads, 16 o's each)
    zvz_body(bid * 256 + t, zp, v2, gamma, vzc);
    grid.sync();

    // phase 4: partial outp (2 units per block)
    for (int rep = 0; rep < 2; ++rep)
        attn_body(bid * 2 + rep, w, lr, lq, qb, kb, vzc, outp);
    grid.sync();

    // phase 5: out = sum outp + xs (262144 float4-units -> 4 reps of 65536)
    for (int rep = 0; rep < 4; ++rep)
        red_body(bid * 256 + t + rep * 65536, outp, xs, out);
}

// ===========================================================================
// Fallback: proven R11 six-kernel path (used if cooperative launch fails)
__global__ __launch_bounds__(256) void k_wcomb(const float* __restrict__ Wsc,
                                               const float* __restrict__ Wv,
                                               float* __restrict__ Wsv) {
    int t = blockIdx.x * 256 + threadIdx.x;
    if (t < OC * CCH) {
        int o = t / CCH, ci = t % CCH;
        float s = 0.f;
        #pragma unroll
        for (int c = 0; c < CCH; ++c) s += Wsc[o * CCH + c] * Wv[c * CCH + ci];
        Wsv[t] = s;
    }
}

__global__ __launch_bounds__(256) void k_proj(
    const float* __restrict__ x1, const float* __restrict__ x2,
    const float* __restrict__ Wq, const float* __restrict__ bq,
    const float* __restrict__ Wk, const float* __restrict__ bk,
    const float* __restrict__ Wsv, const float* __restrict__ Wsc,
    unsigned short* __restrict__ qb, unsigned short* __restrict__ kb,
    float* __restrict__ v2, float* __restrict__ xs) {
    int t = threadIdx.x;
    int g = __builtin_amdgcn_readfirstlane(t >> 6);
    proj_body(blockIdx.x * 64 + (t & 63), g, x1, x2, Wq, bq, Wk, bk,
              Wsv, Wsc, qb, kb, v2, xs);
}

// grid = 1024 x 128 (R11 geometry): virtual wave w = (bid>>6 & 1)*2 + (t>>6)
__global__ __launch_bounds__(128, 4) void k_stats(
    const unsigned short* __restrict__ kb, const unsigned short* __restrict__ qb,
    float* __restrict__ zp) {
    int t = threadIdx.x;
    int l = t & 63;
    int bid = blockIdx.x;
    int unit = (bid & 63) | ((bid >> 7) << 6);
    int w = ((bid >> 6) & 1) * 2 + (t >> 6);
    stats_body(unit, w, l & 15, l >> 4, kb, qb, zp);
}

__global__ __launch_bounds__(256) void k_zvz(const float* __restrict__ zp,
                                             const float* __restrict__ v2,
                                             const float* __restrict__ gamma,
                                             unsigned short* __restrict__ vzc) {
    zvz_body(blockIdx.x * 256 + threadIdx.x, zp, v2, gamma, vzc);
}

__global__ __launch_bounds__(128, 2) void k_attn(
    const unsigned short* __restrict__ qb, const unsigned short* __restrict__ kb,
    const unsigned short* __restrict__ vzc, unsigned short* __restrict__ outp) {
    int t = threadIdx.x;
    int l = t & 63;
    int bid = blockIdx.x;
    int unit = (bid & 63) | ((bid >> 7) << 6);
    int w = ((bid >> 6) & 1) * 2 + (t >> 6);
    attn_body(unit, w, l & 15, l >> 4, qb, kb, vzc, outp);
}

__global__ __launch_bounds__(256) void k_red(const unsigned short* __restrict__ outp,
                                             const float* __restrict__ xs,
                                             float* __restrict__ out) {
    red_body(blockIdx.x * 256 + threadIdx.x, outp, xs, out);
}

// ---------------------------------------------------------------------------
extern "C" void kernel_launch(void* const* d_in, const int* in_sizes, int n_in,
                              void* d_out, int out_size, void* d_ws, size_t ws_size,
                              hipStream_t stream) {
    const float* x1    = (const float*)d_in[0];
    const float* x2    = (const float*)d_in[1];
    const float* Wq    = (const float*)d_in[2];
    const float* bq    = (const float*)d_in[3];
    const float* Wk    = (const float*)d_in[4];
    const float* bk    = (const float*)d_in[5];
    const float* Wv    = (const float*)d_in[6];
    const float* Wsc   = (const float*)d_in[7];
    const float* gamma = (const float*)d_in[8];
    float* out = (float*)d_out;
    float* ws  = (float*)d_ws;

    void* args[] = {&x1, &x2, &Wq, &bq, &Wk, &bk, &Wv, &Wsc, &gamma, &out, &ws};
    hipError_t e = hipLaunchCooperativeKernel((const void*)k_all, dim3(256),
                                              dim3(256), args, 0, stream);
    if (e != hipSuccess) {
        // deterministic fallback: proven R11 six-kernel path
        float*          wsv  = ws + WSV_OFF;
        unsigned short* qbp  = (unsigned short*)(ws + QB_OFF);
        unsigned short* kbp  = (unsigned short*)(ws + KB_OFF);
        float*          xsp  = ws + XS_OFF;
        float*          v2   = ws + V2_OFF;
        float*          zpp  = ws + ZP_OFF;
        unsigned short* vzc  = (unsigned short*)(ws + VZC_OFF);
        unsigned short* outp = (unsigned short*)(ws + OUTP_OFF);

        k_wcomb<<<8, 256, 0, stream>>>(Wsc, Wv, wsv);
        k_proj<<<512, 256, 0, stream>>>(x1, x2, Wq, bq, Wk, bk, wsv, Wsc,
                                        qbp, kbp, v2, xsp);
        k_stats<<<1024, 128, 0, stream>>>(kbp, qbp, zpp);
        k_zvz<<<256, 256, 0, stream>>>(zpp, v2, gamma, vzc);
        k_attn<<<1024, 128, 0, stream>>>(qbp, kbp, vzc, outp);
        k_red<<<1024, 256, 0, stream>>>(outp, xsp, out);
    }
}

// Round 14
// 158.284 us; speedup vs baseline: 2.0943x; 2.0943x over previous
//
#include <hip/hip_runtime.h>

typedef __attribute__((ext_vector_type(8))) __bf16 bf16x8;
typedef __attribute__((ext_vector_type(4))) float f32x4;
typedef _Float16 f16x4 __attribute__((ext_vector_type(4)));
typedef unsigned int uint32;

#define HW   4096
#define CCH  64
#define DQ   32
#define OC   32
#define LOG2E 1.4426950408889634f

// Workspace layout (float offsets). Total ~32.5 MB.
#define WSV_OFF  0u
#define QB_OFF   2048u                    // bf16 [b][n][32] (pre-scaled log2e)
#define KB_OFF   (QB_OFF + 524288u)       // bf16 [b][m][32]
#define XS_OFF   (KB_OFF + 524288u)       // f32  [b][o][n]
#define V2_OFF   (XS_OFF + 1048576u)      // f32  [b][o][m]
#define ZP_OFF   (V2_OFF + 1048576u)      // f32  [8][b][m] partial Z
#define VZC_OFF  (ZP_OFF + 262144u)       // f16  [b][Mb][o][lq][ph][j] shuffled
#define OUTP_OFF (VZC_OFF + 524288u)      // bf16 [8][b][o][n] partial out

__device__ __forceinline__ uint32 f2bf(float x) {   // RNE
    uint32 u = __builtin_bit_cast(uint32, x);
    return (u + 0x7fffu + ((u >> 16) & 1u)) >> 16;
}
// 1-op truncating pack (v_perm_b32): low16 = hi16(a), high16 = hi16(b)
__device__ __forceinline__ uint32 packbf_t(float a, float b) {
    return __builtin_amdgcn_perm(__builtin_bit_cast(uint32, b),
                                 __builtin_bit_cast(uint32, a), 0x07060302u);
}
__device__ __forceinline__ bf16x8 ldfrag(const unsigned short* p) {
    union { uint4 u; bf16x8 f; } t;
    t.u = *(const uint4*)p;
    return t.f;
}
__device__ __forceinline__ bf16x8 asbf(uint4 u) {
    union { uint4 u; bf16x8 f; } t;
    t.u = u;
    return t.f;
}
__device__ __forceinline__ f16x4 u2h4(uint32 a, uint32 b) {
    union { uint2 u; f16x4 f; } t;
    t.u.x = a; t.u.y = b;
    return t.f;
}
__device__ __forceinline__ f16x4 pk4(float a, float b, float c, float d) {
    union { uint2 u; f16x4 f; } t;
    t.u.x = __builtin_bit_cast(uint32, __builtin_amdgcn_cvt_pkrtz(a, b));
    t.u.y = __builtin_bit_cast(uint32, __builtin_amdgcn_cvt_pkrtz(c, d));
    return t.f;
}
__device__ __forceinline__ float fexp2(float x) {
#if __has_builtin(__builtin_amdgcn_exp2f)
    return __builtin_amdgcn_exp2f(x);
#else
    return __expf(x * 0.6931471805599453f);
#endif
}

// ---------------------------------------------------------------------------
// Kernel 0: Wsv = Wsc @ Wv
__global__ __launch_bounds__(256) void k_wcomb(const float* __restrict__ Wsc,
                                               const float* __restrict__ Wv,
                                               float* __restrict__ Wsv) {
    int t = blockIdx.x * 256 + threadIdx.x;
    if (t < OC * CCH) {
        int o = t / CCH, ci = t % CCH;
        float s = 0.f;
        #pragma unroll
        for (int c = 0; c < CCH; ++c) s += Wsc[o * CCH + c] * Wv[c * CCH + ci];
        Wsv[t] = s;
    }
}

// ---------------------------------------------------------------------------
// Kernel 1: projections (R7 geometry, scalar wave-uniform W; trunc bf16 pack)
__global__ __launch_bounds__(256) void k_proj(
    const float* __restrict__ x1, const float* __restrict__ x2,
    const float* __restrict__ Wq, const float* __restrict__ bq,
    const float* __restrict__ Wk, const float* __restrict__ bk,
    const float* __restrict__ Wsv, const float* __restrict__ Wsc,
    unsigned short* __restrict__ qb, unsigned short* __restrict__ kb,
    float* __restrict__ v2, float* __restrict__ xs) {
    int t = threadIdx.x;
    int g = __builtin_amdgcn_readfirstlane(t >> 6);   // wave-uniform
    int l = t & 63;
    int p = blockIdx.x * 64 + l;
    int b = p >> 12, n = p & 4095;
    const float* x1b = x1 + (size_t)b * 32 * HW + n;
    const float* x2b = x2 + (size_t)b * 32 * HW + n;
    float x[CCH];
    #pragma unroll
    for (int c = 0; c < 32; ++c) x[c] = x1b[(size_t)c * HW];
    #pragma unroll
    for (int c = 0; c < 32; ++c) x[32 + c] = x2b[(size_t)c * HW];

    if (g < 2) {
        const float* W    = g ? Wk : Wq;
        const float* bias = g ? bk : bq;
        float scale = g ? 1.0f : LOG2E;
        unsigned short* dst = g ? kb : qb;
        size_t row = ((size_t)b * HW + n) * DQ;
        for (int d0 = 0; d0 < DQ; d0 += 8) {
            float r[8];
            #pragma unroll
            for (int i = 0; i < 8; ++i) {
                const float* wr = W + (d0 + i) * CCH;
                float a = bias[d0 + i];
                #pragma unroll
                for (int c = 0; c < CCH; ++c) a += wr[c] * x[c];
                r[i] = a * scale;
            }
            uint4 u;
            u.x = packbf_t(r[0], r[1]); u.y = packbf_t(r[2], r[3]);
            u.z = packbf_t(r[4], r[5]); u.w = packbf_t(r[6], r[7]);
            *(uint4*)(dst + row + d0) = u;
        }
    } else {
        const float* W = (g == 2) ? Wsv : Wsc;
        float* dst     = (g == 2) ? v2  : xs;
        for (int o = 0; o < OC; ++o) {
            const float* wr = W + o * CCH;
            float a = 0.f;
            #pragma unroll
            for (int c = 0; c < CCH; ++c) a += wr[c] * x[c];
            dst[((size_t)b * OC + o) * HW + n] = a;
        }
    }
}

// ---------------------------------------------------------------------------
// Kernel 2 (R11 verbatim): partial Zp[nc][b][m], 8 resident k-frags,
// q-stream depth-2 prefetch. grid = 1024 x 128.
__global__ __launch_bounds__(128, 4) void k_stats(
    const unsigned short* __restrict__ kb, const unsigned short* __restrict__ qb,
    float* __restrict__ zp) {
    int t = threadIdx.x;
    int w = t >> 6, l = t & 63;
    int lr = l & 15, lq = l >> 4;
    int bid = blockIdx.x;
    int b = bid & 7, nc = (bid >> 3) & 7, mg = bid >> 6;
    int m0 = mg * 256 + w * 128;

    const unsigned short* kbb = kb + (size_t)b * HW * DQ;
    bf16x8 af[8];
    #pragma unroll
    for (int f = 0; f < 8; ++f)
        af[f] = ldfrag(kbb + (size_t)(m0 + f * 16 + lr) * DQ + lq * 8);

    const unsigned short* qp = qb + ((size_t)b * HW + nc * 512 + lr) * DQ + lq * 8;

    f32x4 acc[8];
    #pragma unroll
    for (int f = 0; f < 8; ++f) acc[f] = (f32x4){0.f, 0.f, 0.f, 0.f};
    f32x4 zz = {0.f, 0.f, 0.f, 0.f};

    uint4 q0 = *(const uint4*)qp;
    uint4 q1 = *(const uint4*)(qp + 16 * DQ);
    for (int i = 0; i < 32; ++i) {
        bf16x8 qf = asbf(q0);
        q0 = q1;
        if (i + 2 < 32) q1 = *(const uint4*)(qp + (size_t)(i + 2) * 16 * DQ);
        #pragma unroll
        for (int f = 0; f < 8; ++f) {
            f32x4 s = __builtin_amdgcn_mfma_f32_16x16x32_bf16(af[f], qf, zz, 0, 0, 0);
            acc[f].x += fexp2(s.x); acc[f].y += fexp2(s.y);
            acc[f].z += fexp2(s.z); acc[f].w += fexp2(s.w);
        }
    }
    #pragma unroll
    for (int f = 0; f < 8; ++f) {
        #pragma unroll
        for (int off = 1; off < 16; off <<= 1) {
            acc[f].x += __shfl_xor(acc[f].x, off);
            acc[f].y += __shfl_xor(acc[f].y, off);
            acc[f].z += __shfl_xor(acc[f].z, off);
            acc[f].w += __shfl_xor(acc[f].w, off);
        }
    }
    if (lr == 0) {
        size_t base = (size_t)nc * 32768 + (size_t)b * HW;
        #pragma unroll
        for (int f = 0; f < 8; ++f) {
            size_t p0 = base + m0 + f * 16 + lq * 4;
            zp[p0 + 0] = acc[f].x;
            zp[p0 + 1] = acc[f].y;
            zp[p0 + 2] = acc[f].z;
            zp[p0 + 3] = acc[f].w;
        }
    }
}

// ---------------------------------------------------------------------------
// Kernel 3 (REWRITTEN): zs via LDS, coalesced 64B vzc line writes.
// grid = 128 blocks (8 b x 16 Mb-groups) x 256 thr.
// Phase 1: thread i computes zs[m0+i] into LDS (256 m per group).
// Phase 2: thread = (Mb-local = t>>5, o = t&31) writes one contiguous
// 64B vzc line: element off = lqm*8 + ph*4 + j holds vz[o][ph*16+lqm*4+j].
__global__ __launch_bounds__(256) void k_zvz(const float* __restrict__ zp,
                                             const float* __restrict__ v2,
                                             const float* __restrict__ gamma,
                                             unsigned short* __restrict__ vzc) {
    __shared__ float zsL[256];
    int bid = blockIdx.x;
    int b = bid & 7, mbg = bid >> 3;
    int t = threadIdx.x;
    int m0 = mbg * 256;
    {
        int i = b * HW + m0 + t;
        float s = 0.f;
        #pragma unroll
        for (int nc = 0; nc < 8; ++nc) s += zp[nc * 32768 + i];
        zsL[t] = gamma[0] / s;
    }
    __syncthreads();

    int o = t & 31, mbl = t >> 5;
    int Mb = mbg * 8 + mbl;
    const float* vsrc = v2 + ((size_t)b * OC + o) * HW + Mb * 32;
    float vv[32];
    #pragma unroll
    for (int i = 0; i < 8; ++i) {
        float4 x = *(const float4*)(vsrc + i * 4);
        vv[i * 4 + 0] = x.x; vv[i * 4 + 1] = x.y;
        vv[i * 4 + 2] = x.z; vv[i * 4 + 3] = x.w;
    }
    unsigned short ob[32];
    #pragma unroll
    for (int mloc = 0; mloc < 32; ++mloc) {
        int ph = mloc >> 4, lqm = (mloc >> 2) & 3, j = mloc & 3;
        int off = lqm * 8 + ph * 4 + j;
        _Float16 h = (_Float16)(vv[mloc] * zsL[mbl * 32 + mloc]);
        ob[off] = __builtin_bit_cast(unsigned short, h);
    }
    unsigned short* dst = vzc + (size_t)b * OC * HW + (size_t)Mb * 1024 + o * 32;
    #pragma unroll
    for (int i = 0; i < 4; ++i)
        *(uint4*)(dst + i * 8) = *(uint4*)(ob + i * 8);
}

// ---------------------------------------------------------------------------
__device__ __forceinline__ void attn_step(
    uint4 ck0, uint4 ck1, uint4 cv0, uint4 cv1,
    const bf16x8* qf, f32x4* acc0, f32x4* acc1, f32x4 zz) {
    #pragma unroll
    for (int ph = 0; ph < 2; ++ph) {
        bf16x8 a  = asbf(ph ? ck1 : ck0);
        f16x4 va0 = ph ? u2h4(cv0.z, cv0.w) : u2h4(cv0.x, cv0.y);
        f16x4 va1 = ph ? u2h4(cv1.z, cv1.w) : u2h4(cv1.x, cv1.y);
        #pragma unroll
        for (int tt = 0; tt < 8; ++tt) {
            f32x4 s = __builtin_amdgcn_mfma_f32_16x16x32_bf16(a, qf[tt], zz, 0, 0, 0);
            f16x4 p = pk4(fexp2(s.x), fexp2(s.y), fexp2(s.z), fexp2(s.w));
            acc0[tt] = __builtin_amdgcn_mfma_f32_16x16x16f16(va0, p, acc0[tt], 0, 0, 0);
            acc1[tt] = __builtin_amdgcn_mfma_f32_16x16x16f16(va1, p, acc1[tt], 0, 0, 0);
        }
    }
}

// ---------------------------------------------------------------------------
// Kernel 4 (R11 verbatim): partial outp[mc], wave owns 128 n, depth-2
// prefetch of k/v streams. grid = 1024 x 128.
__global__ __launch_bounds__(128, 2) void k_attn(
    const unsigned short* __restrict__ qb, const unsigned short* __restrict__ kb,
    const unsigned short* __restrict__ vzc, unsigned short* __restrict__ outp) {
    int t = threadIdx.x;
    int w = t >> 6, l = t & 63;
    int lr = l & 15, lq = l >> 4;
    int bid = blockIdx.x;
    int b = bid & 7, mc = (bid >> 3) & 7, ng = bid >> 6;
    int n0 = ng * 256 + w * 128;

    bf16x8 qf[8];
    #pragma unroll
    for (int tt = 0; tt < 8; ++tt)
        qf[tt] = ldfrag(qb + ((size_t)b * HW + n0 + tt * 16 + lr) * DQ + lq * 8);

    const unsigned short* kp = kb + ((size_t)b * HW + lr) * DQ + lq * 8;
    const unsigned short* vp = vzc + (size_t)b * OC * HW + lr * 32 + lq * 8;

    f32x4 acc0[8], acc1[8];
    #pragma unroll
    for (int tt = 0; tt < 8; ++tt) {
        acc0[tt] = (f32x4){0.f, 0.f, 0.f, 0.f};
        acc1[tt] = (f32x4){0.f, 0.f, 0.f, 0.f};
    }
    f32x4 zz = {0.f, 0.f, 0.f, 0.f};

    int mbeg = mc * 512;
    uint4 kA0 = *(const uint4*)(kp + (size_t)mbeg * DQ);
    uint4 kA1 = *(const uint4*)(kp + (size_t)(mbeg + 16) * DQ);
    uint4 vA0 = *(const uint4*)(vp + (size_t)(mbeg >> 5) * 1024);
    uint4 vA1 = *(const uint4*)(vp + (size_t)(mbeg >> 5) * 1024 + 512);
    uint4 kB0 = *(const uint4*)(kp + (size_t)(mbeg + 32) * DQ);
    uint4 kB1 = *(const uint4*)(kp + (size_t)(mbeg + 48) * DQ);
    uint4 vB0 = *(const uint4*)(vp + (size_t)((mbeg + 32) >> 5) * 1024);
    uint4 vB1 = *(const uint4*)(vp + (size_t)((mbeg + 32) >> 5) * 1024 + 512);

    for (int m0 = mbeg; m0 < mbeg + 512; m0 += 64) {
        uint4 ck0 = kA0, ck1 = kA1, cv0 = vA0, cv1 = vA1;
        if (m0 + 64 < mbeg + 512) {
            kA0 = *(const uint4*)(kp + (size_t)(m0 + 64) * DQ);
            kA1 = *(const uint4*)(kp + (size_t)(m0 + 80) * DQ);
            vA0 = *(const uint4*)(vp + (size_t)((m0 + 64) >> 5) * 1024);
            vA1 = *(const uint4*)(vp + (size_t)((m0 + 64) >> 5) * 1024 + 512);
        }
        attn_step(ck0, ck1, cv0, cv1, qf, acc0, acc1, zz);
        ck0 = kB0; ck1 = kB1; cv0 = vB0; cv1 = vB1;
        if (m0 + 96 < mbeg + 512) {
            kB0 = *(const uint4*)(kp + (size_t)(m0 + 96) * DQ);
            kB1 = *(const uint4*)(kp + (size_t)(m0 + 112) * DQ);
            vB0 = *(const uint4*)(vp + (size_t)((m0 + 96) >> 5) * 1024);
            vB1 = *(const uint4*)(vp + (size_t)((m0 + 96) >> 5) * 1024 + 512);
        }
        attn_step(ck0, ck1, cv0, cv1, qf, acc0, acc1, zz);
    }

    unsigned short* ob = outp + (size_t)(mc * 8 + b) * OC * HW;
    #pragma unroll
    for (int tt = 0; tt < 8; ++tt) {
        int n_t = n0 + tt * 16 + lr;
        #pragma unroll
        for (int r = 0; r < 4; ++r) {
            int o0 = lq * 4 + r;
            ob[(size_t)o0 * HW + n_t]        = (unsigned short)f2bf(acc0[tt][r]);
            ob[(size_t)(o0 + 16) * HW + n_t] = (unsigned short)f2bf(acc1[tt][r]);
        }
    }
}

// ---------------------------------------------------------------------------
// Kernel 5 (R11 verbatim): out = sum_mc bf16 outp[mc] + xs
__global__ __launch_bounds__(256) void k_red(const unsigned short* __restrict__ outp,
                                             const float* __restrict__ xs,
                                             float* __restrict__ out) {
    int i = (blockIdx.x * 256 + threadIdx.x) * 4;
    float4 r = *(const float4*)(xs + i);
    const unsigned short* op = outp + i;
    #pragma unroll
    for (int mc = 0; mc < 8; ++mc) {
        uint2 p = *(const uint2*)(op + (size_t)mc * 1048576);
        r.x += __builtin_bit_cast(float, p.x << 16);
        r.y += __builtin_bit_cast(float, p.x & 0xffff0000u);
        r.z += __builtin_bit_cast(float, p.y << 16);
        r.w += __builtin_bit_cast(float, p.y & 0xffff0000u);
    }
    *(float4*)(out + i) = r;
}

// ---------------------------------------------------------------------------
extern "C" void kernel_launch(void* const* d_in, const int* in_sizes, int n_in,
                              void* d_out, int out_size, void* d_ws, size_t ws_size,
                              hipStream_t stream) {
    const float* x1    = (const float*)d_in[0];
    const float* x2    = (const float*)d_in[1];
    const float* Wq    = (const float*)d_in[2];
    const float* bq    = (const float*)d_in[3];
    const float* Wk    = (const float*)d_in[4];
    const float* bk    = (const float*)d_in[5];
    const float* Wv    = (const float*)d_in[6];
    const float* Wsc   = (const float*)d_in[7];
    const float* gamma = (const float*)d_in[8];
    float* out = (float*)d_out;
    float* ws  = (float*)d_ws;

    float*          wsv  = ws + WSV_OFF;
    unsigned short* qbp  = (unsigned short*)(ws + QB_OFF);
    unsigned short* kbp  = (unsigned short*)(ws + KB_OFF);
    float*          xsp  = ws + XS_OFF;
    float*          v2   = ws + V2_OFF;
    float*          zpp  = ws + ZP_OFF;
    unsigned short* vzc  = (unsigned short*)(ws + VZC_OFF);
    unsigned short* outp = (unsigned short*)(ws + OUTP_OFF);

    k_wcomb<<<8, 256, 0, stream>>>(Wsc, Wv, wsv);
    k_proj<<<512, 256, 0, stream>>>(x1, x2, Wq, bq, Wk, bk, wsv, Wsc,
                                    qbp, kbp, v2, xsp);
    k_stats<<<1024, 128, 0, stream>>>(kbp, qbp, zpp);
    k_zvz<<<128, 256, 0, stream>>>(zpp, v2, gamma, vzc);
    k_attn<<<1024, 128, 0, stream>>>(qbp, kbp, vzc, outp);
    k_red<<<1024, 256, 0, stream>>>(outp, xsp, out);
}